// Round 2
// baseline (287.233 us; speedup 1.0000x reference)
//
#include <hip/hip_runtime.h>

// Shapes (fixed): B=1, S=128, Q=256, C=256, H=8, DH=32, TOT=256.
// Inputs/outputs are float32 (per reference). Intermediates in d_ws are bf16.
// MFMA compute in bf16 (threshold is 2% of max|ref| -> plenty of headroom).

typedef unsigned short u16;
typedef unsigned int   u32;
typedef float  f32x4  __attribute__((ext_vector_type(4)));
typedef __bf16 bf16x8 __attribute__((ext_vector_type(8)));

__device__ __forceinline__ float bf2f(u16 u) {
    union { u32 i; float f; } v; v.i = ((u32)u) << 16; return v.f;
}
__device__ __forceinline__ u16 f2bf(float f) {
    union { float f; u32 i; } v; v.f = f;
    u32 r = v.i + 0x7FFFu + ((v.i >> 16) & 1u);   // RNE
    return (u16)(r >> 16);
}

// ---- staging helpers: load 16 contiguous elems as bf16 into dst[16] ----
__device__ __forceinline__ void load16_bf16(const float* src, u16* dst) {
    const float4* p = (const float4*)src;
    float4 f0 = p[0], f1 = p[1], f2 = p[2], f3 = p[3];
    dst[0]  = f2bf(f0.x); dst[1]  = f2bf(f0.y); dst[2]  = f2bf(f0.z); dst[3]  = f2bf(f0.w);
    dst[4]  = f2bf(f1.x); dst[5]  = f2bf(f1.y); dst[6]  = f2bf(f1.z); dst[7]  = f2bf(f1.w);
    dst[8]  = f2bf(f2.x); dst[9]  = f2bf(f2.y); dst[10] = f2bf(f2.z); dst[11] = f2bf(f2.w);
    dst[12] = f2bf(f3.x); dst[13] = f2bf(f3.y); dst[14] = f2bf(f3.z); dst[15] = f2bf(f3.w);
}
__device__ __forceinline__ void load16_bf16(const u16* src, u16* dst) {
    const uint4* p = (const uint4*)src;
    uint4 a0 = p[0], a1 = p[1];
    *(uint4*)&dst[0] = a0; *(uint4*)&dst[8] = a1;
}
__device__ __forceinline__ void store_out(float* p, float v) { *p = v; }
__device__ __forceinline__ void store_out(u16*   p, float v) { *p = f2bf(v); }

// -------------------------------------------------------------------------
// C[m, n] = act( sum_k A[m,k] * W[n,k] + bias[n] )   (fp32 acc, bf16 MFMA)
// M = 32768 (grid.y=256), N = 256 (grid.x=2), K = 256. 128x128 block tile,
// 4 waves in 2x2, each wave 64x64 = 4x4 mfma_f32_16x16x32_bf16 fragments.
// -------------------------------------------------------------------------
template <typename TA, typename TO>
__global__ __launch_bounds__(256) void gemm_bt(
    const TA* __restrict__ A, const float* __restrict__ W,
    const float* __restrict__ bias, TO* __restrict__ out, int act)
{
    __shared__ u16 At[128][40];   // +8 pad: stride 40 -> worst 2-way (free, m136)
    __shared__ u16 Wt[128][40];

    const int m0   = blockIdx.y * 128;
    const int n0   = blockIdx.x * 128;
    const int tid  = threadIdx.x;
    const int lane = tid & 63;
    const int w    = tid >> 6;
    const int quad = lane >> 4;
    const int ln   = lane & 15;
    const int wm   = (w >> 1) * 64;
    const int wn   = (w & 1) * 64;

    f32x4 acc[4][4] = {};

    const int r  = tid >> 1;          // staging row 0..127
    const int c0 = (tid & 1) * 16;    // staging col 0 or 16

    for (int k0 = 0; k0 < 256; k0 += 32) {
        u16 ta[16], tw[16];
        load16_bf16(A + (size_t)(m0 + r) * 256 + k0 + c0, ta);
        load16_bf16(W + (size_t)(n0 + r) * 256 + k0 + c0, tw);
        __syncthreads();              // previous iter's LDS reads drained
        *(uint4*)&At[r][c0] = *(uint4*)&ta[0]; *(uint4*)&At[r][c0 + 8] = *(uint4*)&ta[8];
        *(uint4*)&Wt[r][c0] = *(uint4*)&tw[0]; *(uint4*)&Wt[r][c0 + 8] = *(uint4*)&tw[8];
        __syncthreads();

        bf16x8 af[4], bfr[4];
        #pragma unroll
        for (int i = 0; i < 4; ++i)
            af[i] = __builtin_bit_cast(bf16x8, *(const uint4*)&At[wm + i * 16 + ln][quad * 8]);
        #pragma unroll
        for (int j = 0; j < 4; ++j)
            bfr[j] = __builtin_bit_cast(bf16x8, *(const uint4*)&Wt[wn + j * 16 + ln][quad * 8]);
        #pragma unroll
        for (int i = 0; i < 4; ++i)
            #pragma unroll
            for (int j = 0; j < 4; ++j)
                acc[i][j] = __builtin_amdgcn_mfma_f32_16x16x32_bf16(af[i], bfr[j], acc[i][j], 0, 0, 0);
    }

    #pragma unroll
    for (int i = 0; i < 4; ++i) {
        #pragma unroll
        for (int j = 0; j < 4; ++j) {
            #pragma unroll
            for (int rr = 0; rr < 4; ++rr) {
                const int row = m0 + wm + i * 16 + quad * 4 + rr;  // C/D: row=quad*4+reg
                const int col = n0 + wn + j * 16 + ln;             //      col=lane&15
                float v = acc[i][j][rr];
                if (bias) v += bias[col];
                if (act)  v = 1.0f / (1.0f + __expf(-v));
                store_out(&out[(size_t)row * 256 + col], v);
            }
        }
    }
}

// -------------------------------------------------------------------------
// Attention core. Block = (qt 0..3, h 0..7, s 0..127); 4 waves, wave owns a
// 16-row q m-tile. scores[q,kp] = Q.K^T + bias_mask[s,kp] + bias_pair[h,q,kp]
// -> softmax over kp -> P.V -> *gate -> Ob[sq, h*32+dh] (bf16).
// -------------------------------------------------------------------------
__global__ __launch_bounds__(256) void attn_kernel(
    const u16* __restrict__ Qb, const u16* __restrict__ Kb, const u16* __restrict__ Vb,
    const u16* __restrict__ Gb, const float* __restrict__ bm, const float* __restrict__ bp,
    u16* __restrict__ Ob)
{
    __shared__ u16  Vt[32][264];       // V transposed: Vt[dh][kp]
    __shared__ u16  Pl[4][16][264];    // per-wave P tile (A-layout source)
    __shared__ float bmf[256];

    const int qt   = blockIdx.x;
    const int h    = blockIdx.y;
    const int s    = blockIdx.z;
    const int tid  = threadIdx.x;
    const int lane = tid & 63;
    const int w    = tid >> 6;
    const int quad = lane >> 4;
    const int ln   = lane & 15;

    // stage V^T (thread tid handles key row kp=tid) + bias_mask
    {
        const uint4* vp = (const uint4*)(Vb + (size_t)(s * 256 + tid) * 256 + h * 32);
        uint4 vv0 = vp[0], vv1 = vp[1], vv2 = vp[2], vv3 = vp[3];
        u16 tmp[32];
        *(uint4*)&tmp[0]  = vv0; *(uint4*)&tmp[8]  = vv1;
        *(uint4*)&tmp[16] = vv2; *(uint4*)&tmp[24] = vv3;
        #pragma unroll
        for (int dh = 0; dh < 32; ++dh) Vt[dh][tid] = tmp[dh];
        bmf[tid] = bm[s * 256 + tid];
    }
    __syncthreads();

    const int q0 = qt * 64 + w * 16;

    // Q A-fragment straight from global: A[m=ln][k=quad*8+j], k-dim = DH = 32
    bf16x8 aq = __builtin_bit_cast(bf16x8,
        *(const uint4*)(Qb + (size_t)(s * 256 + q0 + ln) * 256 + h * 32 + quad * 8));

    // scores: one MFMA per 16-col tile (K-dim exactly 32)
    f32x4 sc[16];
    #pragma unroll
    for (int nt = 0; nt < 16; ++nt) {
        bf16x8 bk = __builtin_bit_cast(bf16x8,
            *(const uint4*)(Kb + (size_t)(s * 256 + nt * 16 + ln) * 256 + h * 32 + quad * 8));
        f32x4 z = {0.f, 0.f, 0.f, 0.f};
        sc[nt] = __builtin_amdgcn_mfma_f32_16x16x32_bf16(aq, bk, z, 0, 0, 0);
    }

    // biases + row max   (C/D: row = quad*4+reg, col = nt*16+ln)
    float rmax[4] = {-1e30f, -1e30f, -1e30f, -1e30f};
    #pragma unroll
    for (int nt = 0; nt < 16; ++nt) {
        const int kp = nt * 16 + ln;
        const float bmv = bmf[kp];
        #pragma unroll
        for (int rr = 0; rr < 4; ++rr) {
            const int q = q0 + quad * 4 + rr;
            float v = sc[nt][rr] + bmv + bp[(size_t)(h * 256 + q) * 256 + kp];
            sc[nt][rr] = v;
            rmax[rr] = fmaxf(rmax[rr], v);
        }
    }
    #pragma unroll
    for (int rr = 0; rr < 4; ++rr) {   // reduce across the 16 lanes of the quad
        float m = rmax[rr];
        m = fmaxf(m, __shfl_xor(m, 1));
        m = fmaxf(m, __shfl_xor(m, 2));
        m = fmaxf(m, __shfl_xor(m, 4));
        m = fmaxf(m, __shfl_xor(m, 8));
        rmax[rr] = m;
    }
    float rsum[4] = {0.f, 0.f, 0.f, 0.f};
    #pragma unroll
    for (int nt = 0; nt < 16; ++nt)
        #pragma unroll
        for (int rr = 0; rr < 4; ++rr) {
            float p = __expf(sc[nt][rr] - rmax[rr]);
            sc[nt][rr] = p;
            rsum[rr] += p;
        }
    float rinv[4];
    #pragma unroll
    for (int rr = 0; rr < 4; ++rr) {
        float t = rsum[rr];
        t += __shfl_xor(t, 1);
        t += __shfl_xor(t, 2);
        t += __shfl_xor(t, 4);
        t += __shfl_xor(t, 8);
        rinv[rr] = 1.0f / t;
    }

    // P -> LDS (C-layout write), wave-private region, no barrier needed
    #pragma unroll
    for (int nt = 0; nt < 16; ++nt)
        #pragma unroll
        for (int rr = 0; rr < 4; ++rr)
            Pl[w][quad * 4 + rr][nt * 16 + ln] = f2bf(sc[nt][rr] * rinv[rr]);

    // PV: M=16 q rows, N=32 dh (2 tiles), K=256 kp (8 chunks)
    f32x4 o0 = {0.f, 0.f, 0.f, 0.f}, o1 = {0.f, 0.f, 0.f, 0.f};
    #pragma unroll
    for (int kc = 0; kc < 8; ++kc) {
        bf16x8 pa = __builtin_bit_cast(bf16x8, *(const uint4*)&Pl[w][ln][kc * 32 + quad * 8]);
        bf16x8 v0 = __builtin_bit_cast(bf16x8, *(const uint4*)&Vt[ln][kc * 32 + quad * 8]);
        bf16x8 v1 = __builtin_bit_cast(bf16x8, *(const uint4*)&Vt[16 + ln][kc * 32 + quad * 8]);
        o0 = __builtin_amdgcn_mfma_f32_16x16x32_bf16(pa, v0, o0, 0, 0, 0);
        o1 = __builtin_amdgcn_mfma_f32_16x16x32_bf16(pa, v1, o1, 0, 0, 0);
    }

    // gating + store  (Ob[sq][h*32+dh])
    #pragma unroll
    for (int rr = 0; rr < 4; ++rr) {
        const int q = q0 + quad * 4 + rr;
        const size_t base = (size_t)(s * 256 + q) * 256 + h * 32;
        float g0 = bf2f(Gb[base + ln]);
        float g1 = bf2f(Gb[base + 16 + ln]);
        Ob[base + ln]      = f2bf(o0[rr] * g0);
        Ob[base + 16 + ln] = f2bf(o1[rr] * g1);
    }
}

// -------------------------------------------------------------------------
extern "C" void kernel_launch(void* const* d_in, const int* in_sizes, int n_in,
                              void* d_out, int out_size, void* d_ws, size_t ws_size,
                              hipStream_t stream)
{
    const float* qx  = (const float*)d_in[0];
    const float* kvx = (const float*)d_in[1];
    const float* bm  = (const float*)d_in[2];
    const float* bp  = (const float*)d_in[3];
    const float* Wq  = (const float*)d_in[4];
    const float* Wk  = (const float*)d_in[5];
    const float* Wv  = (const float*)d_in[6];
    const float* Wg  = (const float*)d_in[7];
    const float* bg  = (const float*)d_in[8];
    const float* Wo  = (const float*)d_in[9];
    const float* bo  = (const float*)d_in[10];
    float* out = (float*)d_out;

    // workspace: 5 bf16 buffers of 32768x256 = 83.9 MB total
    const size_t NEL = (size_t)32768 * 256;
    u16* Qb = (u16*)d_ws;
    u16* Kb = Qb + NEL;
    u16* Vb = Kb + NEL;
    u16* Gb = Vb + NEL;
    u16* Ob = Gb + NEL;

    dim3 bb(256);
    dim3 gg(2, 256, 1);
    gemm_bt<float, u16><<<gg, bb, 0, stream>>>(qx,  Wq, (const float*)nullptr, Qb, 0);
    gemm_bt<float, u16><<<gg, bb, 0, stream>>>(kvx, Wk, (const float*)nullptr, Kb, 0);
    gemm_bt<float, u16><<<gg, bb, 0, stream>>>(kvx, Wv, (const float*)nullptr, Vb, 0);
    gemm_bt<float, u16><<<gg, bb, 0, stream>>>(qx,  Wg, bg,                    Gb, 1);

    dim3 ga(4, 8, 128);
    attn_kernel<<<ga, bb, 0, stream>>>(Qb, Kb, Vb, Gb, bm, bp, Ob);

    gemm_bt<u16, float><<<gg, bb, 0, stream>>>(Ob, Wo, bo, out, 0);
}